// Round 8
// baseline (67.648 us; speedup 1.0000x reference)
//
#include <hip/hip_runtime.h>

// Problem constants (from reference): B=4, C=64, G=64, P=8, S=G*P=512
constexpr int Bn = 4;
constexpr int Cn = 64;
constexpr int Gn = 64;
constexpr int Pn = 8;
constexpr int Sn = Gn * Pn;          // 512

constexpr int COLS = Gn + 2;         // 66 staged fea columns (full row + halo)
constexpr int LDC  = 68;             // padded channel stride (float)

// native vector type: __builtin_nontemporal_* requires it (HIP float4 is a class)
typedef float f32x4 __attribute__((ext_vector_type(4)));

// out[b,c,y,x] = sum_{dy,dx} prob[b, 3*dy+dx, y, x] * fea[b, ch*G+cw, c]
// Full-row blocks: block=(b,h), 512 threads; thread = (row 0..3, xg 0..127),
// two row-passes. Wave stores are 1KB contiguous; wave-pairs cover full 2KB
// plane rows -> better DRAM page locality than the 512B fragments of R1-R7.
__global__ __launch_bounds__(512, 2)
void sp_upsample_kernel(const float* __restrict__ fea,
                        const float* __restrict__ prob,
                        float* __restrict__ out) {
    __shared__ float fea_lds[3 * COLS * LDC];   // 53856 B

    const int bx  = blockIdx.x;
    const int h   = bx & (Gn - 1);          // grid row
    const int b   = bx >> 6;                // batch
    const int tid = threadIdx.x;

    // ---- stage fea: rows h-1..h+1 (clamped), all 66 cols (clamped), 64 ch
    constexpr int NVEC = 3 * COLS * (Cn / 4);   // 3168 float4s
    for (int idx = tid; idx < NVEC; idx += 512) {
        const int c4   = idx & 15;          // channel group
        const int colr = idx >> 4;          // 0..197
        const int col  = colr % COLS;
        const int r    = colr / COLS;
        const int gh = min(max(h - 1 + r, 0), Gn - 1);
        const int gw = min(max(col - 1, 0), Gn - 1);
        const f32x4 v = *reinterpret_cast<const f32x4*>(
            fea + ((size_t)(b * Gn * Gn + gh * Gn + gw)) * Cn + c4 * 4);
        *reinterpret_cast<f32x4*>(&fea_lds[(r * COLS + col) * LDC + c4 * 4]) = v;
    }
    __syncthreads();

    // ---- thread mapping: xg = tid&127 (4 consecutive x), row = tid>>7 (0..3)
    const int xg   = tid & 127;
    const int row  = tid >> 7;
    const int x    = xg * 4;
    const int cell = xg >> 1;               // 0..63
    const size_t SS = (size_t)Sn * Sn;

    #pragma unroll 1
    for (int rp = 0; rp < 2; ++rp) {
        const int y = h * Pn + rp * 4 + row;
        const size_t yoff = (size_t)y * Sn + x;

        // load prob: 9 neighbors x 4 x-positions (dwordx4, streaming, 1KB/wave-instr)
        f32x4 p[9];
        const float* pb = prob + (size_t)b * 9 * SS + yoff;
        #pragma unroll
        for (int k = 0; k < 9; ++k)
            p[k] = __builtin_nontemporal_load(
                reinterpret_cast<const f32x4*>(pb + (size_t)k * SS));

        float* ob = out + (size_t)b * Cn * SS + yoff;

        #pragma unroll 1
        for (int c4 = 0; c4 < Cn / 4; ++c4) {
            // 9 neighbor fea float4s for this channel group
            f32x4 f[9];
            #pragma unroll
            for (int k = 0; k < 9; ++k) {
                const int dy = k / 3, dx = k % 3;   // compile-time
                f[k] = *reinterpret_cast<const f32x4*>(
                    &fea_lds[(dy * COLS + cell + dx) * LDC + c4 * 4]);
            }
            // acc[j] = f32x4 over 4 x-positions for channel c4*4+j
            f32x4 acc[4];
            #pragma unroll
            for (int j = 0; j < 4; ++j) acc[j] = (f32x4)(0.f);
            #pragma unroll
            for (int k = 0; k < 9; ++k) {
                const f32x4 fk = f[k];
                const f32x4 pk = p[k];
                #pragma unroll
                for (int j = 0; j < 4; ++j) {
                    acc[j].x = fmaf(pk.x, fk[j], acc[j].x);
                    acc[j].y = fmaf(pk.y, fk[j], acc[j].y);
                    acc[j].z = fmaf(pk.z, fk[j], acc[j].z);
                    acc[j].w = fmaf(pk.w, fk[j], acc[j].w);
                }
            }
            #pragma unroll
            for (int j = 0; j < 4; ++j)
                __builtin_nontemporal_store(acc[j],
                    reinterpret_cast<f32x4*>(ob + (size_t)(c4 * 4 + j) * SS));
        }
    }
}

extern "C" void kernel_launch(void* const* d_in, const int* in_sizes, int n_in,
                              void* d_out, int out_size, void* d_ws, size_t ws_size,
                              hipStream_t stream) {
    const float* fea  = (const float*)d_in[0];   // [4, 4096, 64]
    const float* prob = (const float*)d_in[1];   // [4, 9, 512, 512]
    float* out = (float*)d_out;                  // [4, 64, 512, 512]

    const int grid = Bn * Gn;                    // 256 blocks (one per CU)
    sp_upsample_kernel<<<grid, 512, 0, stream>>>(fea, prob, out);
}

// Round 9
// 63.871 us; speedup vs baseline: 1.0591x; 1.0591x over previous
//
#include <hip/hip_runtime.h>
#include <stdint.h>

// Problem constants: B=4, C=64, G=64, P=8, S=512
constexpr int Bn = 4;
constexpr int Cn = 64;
constexpr int Gn = 64;
constexpr int Pn = 8;
constexpr int Sn = Gn * Pn;          // 512

constexpr int CPB   = 16;            // cells per tile along x
constexpr int XSPAN = CPB * Pn;      // 128 output columns per tile
constexpr int PAIRW = 2 * CPB;       // 32 cells per block (2 tiles)
constexpr int COLS  = PAIRW + 2;     // 34 staged fea columns (pair + halo)
constexpr int LDC   = 68;            // padded channel stride (float)

typedef float f32x4 __attribute__((ext_vector_type(4)));
typedef const __attribute__((address_space(1))) uint32_t gu32;
typedef __attribute__((address_space(3)))       uint32_t lu32;

// Per-tile compute: R5's proven path (scalar nt stores, LDS f-broadcast).
__device__ __forceinline__ void tile_compute(const float* fea_lds,
                                             const float (&p)[4][9],
                                             int cell, float* obase, size_t SS) {
    #pragma unroll 1
    for (int c4 = 0; c4 < Cn / 4; ++c4) {
        f32x4 f[9];
        #pragma unroll
        for (int k = 0; k < 9; ++k) {
            const int dy = k / 3, dx = k % 3;   // compile-time
            f[k] = *reinterpret_cast<const f32x4*>(
                &fea_lds[(dy * COLS + cell + dx) * LDC + c4 * 4]);
        }
        f32x4 acc[4];
        #pragma unroll
        for (int r = 0; r < 4; ++r) acc[r] = (f32x4)(0.f);
        #pragma unroll
        for (int k = 0; k < 9; ++k) {
            #pragma unroll
            for (int r = 0; r < 4; ++r) {
                acc[r].x = fmaf(p[r][k], f[k].x, acc[r].x);
                acc[r].y = fmaf(p[r][k], f[k].y, acc[r].y);
                acc[r].z = fmaf(p[r][k], f[k].z, acc[r].z);
                acc[r].w = fmaf(p[r][k], f[k].w, acc[r].w);
            }
        }
        #pragma unroll
        for (int r = 0; r < 4; ++r) {
            const size_t base = (size_t)(c4 * 4) * SS + (size_t)r * Sn;
            __builtin_nontemporal_store(acc[r].x, obase + base);
            __builtin_nontemporal_store(acc[r].y, obase + base + SS);
            __builtin_nontemporal_store(acc[r].z, obase + base + 2 * SS);
            __builtin_nontemporal_store(acc[r].w, obase + base + 3 * SS);
        }
    }
}

// Two x-tiles per block, shared fea staging; tile1's prob prefetched into LDS
// via global_load_lds (no VGPR cost) under tile0's store phase.
__global__ __launch_bounds__(256, 2)
void sp_upsample_kernel(const float* __restrict__ fea,
                        const float* __restrict__ prob,
                        float* __restrict__ out) {
    __shared__ float fea_lds[3 * COLS * LDC];   // 27744 B
    __shared__ float p_lds[9][Pn][XSPAN];       // 36864 B

    const int bx  = blockIdx.x;
    const int pr  = bx & 1;                 // tile-pair (x half) 0..1
    const int h   = (bx >> 1) & (Gn - 1);   // grid row
    const int b   = bx >> 7;                // batch
    const int w0  = pr * PAIRW;             // first cell col of pair
    const int tid = threadIdx.x;
    const size_t SS = (size_t)Sn * Sn;

    // ---- stage fea for BOTH tiles: rows h-1..h+1, cols w0-1..w0+32 (clamped)
    constexpr int NVEC = 3 * COLS * (Cn / 4);   // 1632 float4s
    for (int idx = tid; idx < NVEC; idx += 256) {
        const int c4   = idx & 15;
        const int colr = idx >> 4;
        const int col  = colr % COLS;
        const int r    = colr / COLS;
        const int gh = min(max(h - 1 + r, 0), Gn - 1);
        const int gw = min(max(w0 - 1 + col, 0), Gn - 1);
        const f32x4 v = *reinterpret_cast<const f32x4*>(
            fea + ((size_t)(b * Gn * Gn + gh * Gn + gw)) * Cn + c4 * 4);
        *reinterpret_cast<f32x4*>(&fea_lds[(r * COLS + col) * LDC + c4 * 4]) = v;
    }
    __syncthreads();

    const int xl    = tid & (XSPAN - 1);    // 0..127
    const int p1q   = tid >> 7;             // 0..1
    const int ybase = h * Pn + p1q * 4;
    const int lane  = tid & 63;
    const int wv    = tid >> 6;             // wave id 0..3
    const int x0    = pr * 256 + xl;        // tile0 output column

    // ---- tile0 prob: scalar nt loads into registers (issued FIRST)
    float p0[4][9];
    {
        const float* pb = prob + (size_t)b * 9 * SS + (size_t)ybase * Sn + x0;
        #pragma unroll
        for (int r = 0; r < 4; ++r)
            #pragma unroll
            for (int k = 0; k < 9; ++k)
                p0[r][k] = __builtin_nontemporal_load(pb + (size_t)r * Sn + (size_t)k * SS);
    }
    __builtin_amdgcn_sched_barrier(0);

    // ---- prefetch tile1 prob -> LDS (fire-and-forget; completes under stores)
    // 144 chunks of 256B (k 0..8, y 0..7, half 0..1), 36 per wave.
    {
        const float* pbase = prob + (size_t)b * 9 * SS;
        const int x01 = pr * 256 + XSPAN;
        for (int j = wv; j < 144; j += 4) {
            const int k    = j >> 4;        // 0..8
            const int rem  = j & 15;
            const int y    = rem >> 1;      // 0..7
            const int half = rem & 1;
            const float* g = pbase + (size_t)k * SS + (size_t)(h * Pn + y) * Sn
                             + x01 + half * 64 + lane;
            __builtin_amdgcn_global_load_lds((gu32*)g, (lu32*)&p_lds[k][y][half * 64],
                                             4, 0, 0);
        }
    }
    __builtin_amdgcn_sched_barrier(0);

    // ---- tile0 compute/store (cells 0..15 of the pair)
    float* ob0 = out + (size_t)b * Cn * SS + (size_t)ybase * Sn + x0;
    tile_compute(fea_lds, p0, (xl >> 3), ob0, SS);

    __syncthreads();   // barrier drain (vmcnt 0) -> p_lds ready

    // ---- tile1: prob from LDS (conflict-free b32), then compute/store
    float p1[4][9];
    #pragma unroll
    for (int r = 0; r < 4; ++r)
        #pragma unroll
        for (int k = 0; k < 9; ++k)
            p1[r][k] = p_lds[k][p1q * 4 + r][xl];

    float* ob1 = ob0 + XSPAN;
    tile_compute(fea_lds, p1, CPB + (xl >> 3), ob1, SS);
}

extern "C" void kernel_launch(void* const* d_in, const int* in_sizes, int n_in,
                              void* d_out, int out_size, void* d_ws, size_t ws_size,
                              hipStream_t stream) {
    const float* fea  = (const float*)d_in[0];   // [4, 4096, 64]
    const float* prob = (const float*)d_in[1];   // [4, 9, 512, 512]
    float* out = (float*)d_out;                  // [4, 64, 512, 512]

    const int grid = Bn * Gn * 2;                // 512 blocks (2 tiles each)
    sp_upsample_kernel<<<grid, 256, 0, stream>>>(fea, prob, out);
}